// Round 6
// baseline (169.244 us; speedup 1.0000x reference)
//
#include <hip/hip_runtime.h>
#include <hip/hip_bf16.h>

typedef __bf16 bf16x8_t __attribute__((ext_vector_type(8)));
typedef float f32x4_t __attribute__((ext_vector_type(4)));
using bf16 = __hip_bfloat16;

__device__ __forceinline__ unsigned short f2bf_bits(float v) {
  __hip_bfloat16 h = __float2bfloat16(v);
  return *reinterpret_cast<unsigned short*>(&h);
}

// mish(x) = x*tanh(softplus(x)) = x*n/(n+2) with n = e^x*(e^x+2).
__device__ __forceinline__ float mish_f(float x) {
  float z = __expf(x);
  float n = z * (z + 2.0f);
  float m = x * n / (n + 2.0f);
  return (x > 10.0f) ? x : m;
}

// Counted-wait barrier: orders LDS (lgkmcnt) but does NOT drain outstanding
// global loads (vmcnt) -> the rolling q-register weight FIFO stays in flight
// across chunk barriers. (Raw s_barrier does not force vmcnt(0); the compiler
// only waits at actual USE points of loaded values.)
__device__ __forceinline__ void bar() {
  asm volatile("s_waitcnt lgkmcnt(0)" ::: "memory");
  __builtin_amdgcn_s_barrier();
  asm volatile("" ::: "memory");
}

// sched_barrier mask: allow ALU|VALU|SALU|MFMA|DS|DS_READ|DS_WRITE to cross,
// block only VMEM (0x10|0x20|0x40). Pins global-load ISSUE order/placement
// without restricting MFMA/DS scheduling.
#define SB_PIN_VMEM() __builtin_amdgcn_sched_barrier(0x38F)

// One consumer k-step, 2-col phases (B,C). Plain loads (compiler inserts the
// counted vmcnt waits); SB_PIN_VMEM keeps the issue 6 ksteps ahead of use.
// NKK is always KK+6 (or -1), so the new pair lands in slot (KK)%6.
#define KSTEP2(WPTR, AC, KK, KS, NKK)                                          \
  do {                                                                         \
    bf16x8_t nb0_, nb1_;                                                       \
    if ((NKK) >= 0) {                                                          \
      const bf16* p_ = (WPTR) + (size_t)((NKK) * 16 + ntg0) * 512 + foff;      \
      nb0_ = *(const bf16x8_t*)p_;                                             \
      nb1_ = *(const bf16x8_t*)(p_ + 512);                                     \
    }                                                                          \
    SB_PIN_VMEM();                                                             \
    bf16x8_t a0_ = *(const bf16x8_t*)((AC) + lr * 232 + (KS) * 32 + quad * 8); \
    bf16x8_t a1_ =                                                             \
        *(const bf16x8_t*)((AC) + (16 + lr) * 232 + (KS) * 32 + quad * 8);     \
    bf16x8_t b0_ = q0[(KK) % 6];                                               \
    bf16x8_t b1_ = q1[(KK) % 6];                                               \
    acc[0][0] = __builtin_amdgcn_mfma_f32_16x16x32_bf16(a0_, b0_, acc[0][0], 0, 0, 0); \
    acc[0][1] = __builtin_amdgcn_mfma_f32_16x16x32_bf16(a0_, b1_, acc[0][1], 0, 0, 0); \
    acc[1][0] = __builtin_amdgcn_mfma_f32_16x16x32_bf16(a1_, b0_, acc[1][0], 0, 0, 0); \
    acc[1][1] = __builtin_amdgcn_mfma_f32_16x16x32_bf16(a1_, b1_, acc[1][1], 0, 0, 0); \
    if ((NKK) >= 0) { q0[(KK) % 6] = nb0_; q1[(KK) % 6] = nb1_; }              \
  } while (0)

// One consumer k-step for phase E (1 col, wave w owns k-slot w). 4-deep.
#define KSTEP1(AC, CC, NKK)                                                    \
  do {                                                                         \
    bf16x8_t nb_;                                                              \
    if ((NKK) >= 0) {                                                          \
      nb_ = *(const bf16x8_t*)(W3f + (size_t)((NKK) * 7 + w) * 512 + foff);    \
    }                                                                          \
    SB_PIN_VMEM();                                                             \
    bf16x8_t a0_ = *(const bf16x8_t*)((AC) + lr * 232 + w * 32 + quad * 8);    \
    bf16x8_t a1_ = *(const bf16x8_t*)((AC) + (16 + lr) * 232 + w * 32 + quad * 8); \
    bf16x8_t b_ = q3[(CC) % 4];                                                \
    acc3[0] = __builtin_amdgcn_mfma_f32_16x16x32_bf16(a0_, b_, acc3[0], 0, 0, 0); \
    acc3[1] = __builtin_amdgcn_mfma_f32_16x16x32_bf16(a1_, b_, acc3[1], 0, 0, 0); \
    if ((NKK) >= 0) q3[(CC) % 4] = nb_;                                        \
  } while (0)

// 13 cubic B-spline basis values (grid 10, k=3, [-2,2]) + mish -> 28B LDS
// region. Round-0 sparse-store version (branch-free selects doubled VALUBusy
// in round 4 — reverted for good).
__device__ __forceinline__ void kan_feats28(bf16* dst, float x) {
  unsigned int* d32 = (unsigned int*)dst;
#pragma unroll
  for (int d = 0; d < 7; ++d) d32[d] = 0u;
  float t = (x + 3.2f) * 2.5f;
  if (t >= 0.0f && t < 16.0f) {
    float tf = floorf(t);
    int c = (int)tf;
    float u = t - tf;
    float um = 1.0f - u;
    float u2 = u * u, u3 = u2 * u;
    const float s6 = 1.0f / 6.0f;
    float w0 = um * um * um * s6;
    float w1 = (3.0f * u3 - 6.0f * u2 + 4.0f) * s6;
    float w2 = (-3.0f * u3 + 3.0f * u2 + 3.0f * u + 1.0f) * s6;
    float w3 = u3 * s6;
    int j0 = c - 3;
    if (j0 >= 0)               dst[j0]     = __float2bfloat16(w0);
    if (j0 >= -1 && j0 <= 11)  dst[j0 + 1] = __float2bfloat16(w1);
    if (j0 >= -2 && j0 <= 10)  dst[j0 + 2] = __float2bfloat16(w2);
    if (j0 <= 9)               dst[j0 + 3] = __float2bfloat16(w3);
  }
  dst[13] = __float2bfloat16(mish_f(x));
}

// Builds W1f, W2f, W3f — ALL MFMA-fragment-major. Frag s (global k-frag of 32)
// x ntg (group of 16 N-rows): 512 elements (1KB); element (n,quad,el) at
// (s*16+ntg)*512 + n*32 + quad*8 + el. Packed grid (322 blocks).
__global__ __launch_bounds__(256) void prep_all(
    const float* __restrict__ c1, const float* __restrict__ sb1, const float* __restrict__ sp1,
    const float* __restrict__ c2, const float* __restrict__ sb2, const float* __restrict__ sp2,
    const float* __restrict__ c3, const float* __restrict__ sb3, const float* __restrict__ sp3,
    bf16* __restrict__ W1f, bf16* __restrict__ W2f, bf16* __restrict__ W3f) {
  const int b = blockIdx.x, t = threadIdx.x;
  float vals[14];
  if (b < 49) {
    const int i = b, o = t;
    const int ntg = o >> 4, lrr = o & 15;
    const size_t io = (size_t)i * 256 + o;
    const float spv = sp1[io];
#pragma unroll
    for (int r = 0; r < 13; ++r) vals[r] = c1[io * 13 + r] * spv;
    vals[13] = sb1[io];
#pragma unroll
    for (int d = 0; d < 7; ++d) {
      const int k2 = i * 14 + 2 * d;
      const int s = k2 >> 5, r2 = k2 & 31;
      const size_t off = ((size_t)(s * 16 + ntg)) * 512 + lrr * 32 + (r2 >> 3) * 8 + (r2 & 7);
      *(unsigned int*)(W1f + off) = (unsigned int)f2bf_bits(vals[2 * d]) |
                                    ((unsigned int)f2bf_bits(vals[2 * d + 1]) << 16);
    }
  } else if (b == 49) {
    const int ntg = t >> 4, lrr = t & 15;
#pragma unroll
    for (int d = 0; d < 9; ++d) {
      const int k2 = 686 + 2 * d;
      const int r2 = k2 & 31;
      *(unsigned int*)(W1f + ((size_t)(21 * 16 + ntg)) * 512 + lrr * 32 + (r2 >> 3) * 8 + (r2 & 7)) = 0u;
    }
  } else if (b < 306) {
    const int i = b - 50;
    const int o = t;
    const int ntg = o >> 4, lrr = o & 15;
    const size_t io = (size_t)i * 256 + o;
    const float spv = sp2[io];
#pragma unroll
    for (int r = 0; r < 13; ++r) vals[r] = c2[io * 13 + r] * spv;
    vals[13] = sb2[io];
#pragma unroll
    for (int d = 0; d < 7; ++d) {
      const int k2 = i * 14 + 2 * d;
      const int s = k2 >> 5, r2 = k2 & 31;
      const size_t off = ((size_t)(s * 16 + ntg)) * 512 + lrr * 32 + (r2 >> 3) * 8 + (r2 & 7);
      *(unsigned int*)(W2f + off) = (unsigned int)f2bf_bits(vals[2 * d]) |
                                    ((unsigned int)f2bf_bits(vals[2 * d + 1]) << 16);
    }
  } else {
    const int idx = (b - 306) * 256 + t;  // 4096 items: i in [0,256), o in [0,16)
    const int i = idx >> 4, o = idx & 15;
    if (o < 10) {
      const size_t io = (size_t)i * 10 + o;
      const float spv = sp3[io];
#pragma unroll
      for (int r = 0; r < 13; ++r) vals[r] = c3[io * 13 + r] * spv;
      vals[13] = sb3[io];
#pragma unroll
      for (int d = 0; d < 7; ++d) {
        const int k2 = i * 14 + 2 * d;
        const int s = k2 >> 5, r2 = k2 & 31;
        const size_t off = (size_t)s * 512 + o * 32 + (r2 >> 3) * 8 + (r2 & 7);
        *(unsigned int*)(W3f + off) = (unsigned int)f2bf_bits(vals[2 * d]) |
                                      ((unsigned int)f2bf_bits(vals[2 * d + 1]) << 16);
      }
    } else {
#pragma unroll
      for (int d = 0; d < 7; ++d) {
        const int k2 = i * 14 + 2 * d;
        const int s = k2 >> 5, r2 = k2 & 31;
        *(unsigned int*)(W3f + (size_t)s * 512 + o * 32 + (r2 >> 3) * 8 + (r2 & 7)) = 0u;
      }
    }
  }
}

// Megakernel v11: round-0 structure + 6-deep plain-load weight FIFO pinned by
// sched_barrier (VMEM-only), lgkm-only barriers. 256 blocks x 1024 thr.
// Consumers (waves 0..7) own 32 cols each and do ALL MFMAs; producers
// (waves 8..15) compute chunk c+1 feats while consumers crunch chunk c.
__global__ __launch_bounds__(1024, 4) void meganet(
    const float* __restrict__ x, const bf16* __restrict__ W1f,
    const bf16* __restrict__ W2f, const bf16* __restrict__ W3f,
    const float* __restrict__ b1, const float* __restrict__ b2,
    const float* __restrict__ b3, float* __restrict__ out) {
  __shared__ __align__(16) char lds[73728];
  float* const Hs = (float*)lds;             // [256][36] f32 transposed
  bf16* const Ach0 = (bf16*)(lds + 36864);   // [32][232] bf16
  bf16* const Ach1 = (bf16*)(lds + 51712);
  float* const P = (float*)(lds + 66560);    // [32][56] f32
  float* const xs = (float*)lds;             // phase A only (50176 B)
  float* const Red = (float*)(lds + 36864);  // [7][32][16] f32 (E tail)
  float* const V = (float*)(lds + 51712);    // 32x16 f32

  const int t = threadIdx.x;
  const int w = t >> 6, lane = t & 63, quad = lane >> 4, lr = lane & 15;
  const int tr = (t >> 4) & 31, ej = t & 15;  // producer eval coords (t>=512)
  const int r0 = blockIdx.x * 32;
  const int foff = lr * 32 + quad * 8;
  const bool cons = (w < 8);
  const int ntg0 = 2 * w;  // consumer col-group base (valid w<8)

  // ---- Phase A: pool 32 images -> P[32][56] (staged via LDS) ----
  for (int h = 0; h < 2; ++h) {
    const float4* src = (const float4*)x + (size_t)(r0 + h * 16) * 196;
    float4* xd = (float4*)xs;
#pragma unroll
    for (int l = 0; l < 4; ++l) {
      const int idx = t + l * 1024;
      if (idx < 3136) xd[idx] = src[idx];
    }
    bar();
    if (t < 784) {
      const int img = t / 49, p = t - img * 49;
      const int oh = p / 7, ow = p - oh * 7;
      const float* xi = xs + img * 784 + oh * 112 + ow * 4;
      f32x4_t s4 = (f32x4_t){0.f, 0.f, 0.f, 0.f};
#pragma unroll
      for (int rr = 0; rr < 4; ++rr) {
        const f32x4_t v = *(const f32x4_t*)(xi + rr * 28);  // 16B-aligned
        s4 += v;
      }
      P[(h * 16 + img) * 56 + p] = (s4[0] + s4[1] + s4[2] + s4[3]) * (1.0f / 16.0f);
    }
    bar();
  }

  f32x4_t acc[2][2];
#pragma unroll
  for (int m = 0; m < 2; ++m)
#pragma unroll
    for (int n = 0; n < 2; ++n) acc[m][n] = (f32x4_t){0.f, 0.f, 0.f, 0.f};

  bf16x8_t q0[6], q1[6];

  // ---- Phase B: layer-1, K=704 (22 k-frags: chunks 7,7,7,1) ----
  if (cons) {
#pragma unroll
    for (int s = 0; s < 6; ++s) {
      const bf16* p_ = W1f + (size_t)(s * 16 + ntg0) * 512 + foff;
      q0[s] = *(const bf16x8_t*)p_;
      q1[s] = *(const bf16x8_t*)(p_ + 512);
    }
    SB_PIN_VMEM();
  } else {
    kan_feats28(Ach0 + tr * 232 + ej * 14, P[tr * 56 + ej]);  // chunk 0
  }
  bar();
#pragma unroll
  for (int c = 0; c < 4; ++c) {
    const bf16* const Ac = (c & 1) ? Ach1 : Ach0;
    bf16* const An = (c & 1) ? Ach0 : Ach1;
    if (cons) {
      if (c < 2) {
#pragma unroll
        for (int ks = 0; ks < 7; ++ks) {
          const int kk = c * 7 + ks;
          KSTEP2(W1f, Ac, kk, ks, kk + 6);
        }
      } else if (c == 2) {
        KSTEP2(W1f, Ac, 14, 0, 20);
        KSTEP2(W1f, Ac, 15, 1, 21);
        KSTEP2(W1f, Ac, 16, 2, -1);
        KSTEP2(W1f, Ac, 17, 3, -1);
        KSTEP2(W1f, Ac, 18, 4, -1);
        KSTEP2(W1f, Ac, 19, 5, -1);
        KSTEP2(W1f, Ac, 20, 6, -1);
      } else {
        KSTEP2(W1f, Ac, 21, 0, -1);
      }
    } else {
      if (c < 2) {
        kan_feats28(An + tr * 232 + ej * 14, P[tr * 56 + (c + 1) * 16 + ej]);
      } else if (c == 2) {
        if (ej == 0) kan_feats28(An + tr * 232, P[tr * 56 + 48]);
        else if (ej == 1) {
          unsigned int* z = (unsigned int*)(An + tr * 232 + 14);
#pragma unroll
          for (int d = 0; d < 9; ++d) z[d] = 0u;  // pad k 686..703
        }
      }
    }
    bar();
  }
  // H1 = acc + b1 -> Hs (transposed); consumers cover all 256 cols
  if (cons) {
#pragma unroll
    for (int m = 0; m < 2; ++m)
#pragma unroll
      for (int n = 0; n < 2; ++n) {
        const int col = w * 32 + n * 16 + lr;
        const float bn = b1[col];
        f32x4_t v;
#pragma unroll
        for (int r = 0; r < 4; ++r) v[r] = acc[m][n][r] + bn;
        *(f32x4_t*)(Hs + col * 36 + m * 16 + quad * 4) = v;
      }
  }
  bar();

  // ---- Phase C: layer-2, K=3584 (16 chunks x 7 frags) ----
#pragma unroll
  for (int m = 0; m < 2; ++m)
#pragma unroll
    for (int n = 0; n < 2; ++n) acc[m][n] = (f32x4_t){0.f, 0.f, 0.f, 0.f};
  if (cons) {
#pragma unroll
    for (int s = 0; s < 6; ++s) {
      const bf16* p_ = W2f + (size_t)(s * 16 + ntg0) * 512 + foff;
      q0[s] = *(const bf16x8_t*)p_;
      q1[s] = *(const bf16x8_t*)(p_ + 512);
    }
    SB_PIN_VMEM();
  } else {
    kan_feats28(Ach0 + tr * 232 + ej * 14, Hs[ej * 36 + tr]);  // chunk 0
  }
  bar();
#pragma unroll
  for (int c = 0; c < 16; ++c) {
    const bf16* const Ac = (c & 1) ? Ach1 : Ach0;
    bf16* const An = (c & 1) ? Ach0 : Ach1;
    if (cons) {
      if (c < 15) {
#pragma unroll
        for (int ks = 0; ks < 7; ++ks) {
          const int kk = c * 7 + ks;
          KSTEP2(W2f, Ac, kk, ks, kk + 6);  // max issue 104+6=110 < 112
        }
      } else {
        KSTEP2(W2f, Ac, 105, 0, 111);
        KSTEP2(W2f, Ac, 106, 1, -1);
        KSTEP2(W2f, Ac, 107, 2, -1);
        KSTEP2(W2f, Ac, 108, 3, -1);
        KSTEP2(W2f, Ac, 109, 4, -1);
        KSTEP2(W2f, Ac, 110, 5, -1);
        KSTEP2(W2f, Ac, 111, 6, -1);
      }
    } else if (c < 15) {
      kan_feats28(An + tr * 232 + ej * 14, Hs[((c + 1) * 16 + ej) * 36 + tr]);
    }
    bar();
  }
  // H2 = acc + b2 -> Hs (overwrite; H1 dead after chunk-15 feats)
  if (cons) {
#pragma unroll
    for (int m = 0; m < 2; ++m)
#pragma unroll
      for (int n = 0; n < 2; ++n) {
        const int col = w * 32 + n * 16 + lr;
        const float bn = b2[col];
        f32x4_t v;
#pragma unroll
        for (int r = 0; r < 4; ++r) v[r] = acc[m][n][r] + bn;
        *(f32x4_t*)(Hs + col * 36 + m * 16 + quad * 4) = v;
      }
  }
  bar();

  // ---- Phase E: layer-3 (N=16, 10 real). Consumers = waves 0..6 (one ks
  //      each, both m-halves); producers = waves 8..15. ----
  f32x4_t acc3[2];
  acc3[0] = (f32x4_t){0.f, 0.f, 0.f, 0.f};
  acc3[1] = acc3[0];
  bf16x8_t q3[4];
  if (w < 7) {
#pragma unroll
    for (int s = 0; s < 4; ++s)
      q3[s] = *(const bf16x8_t*)(W3f + (size_t)(s * 7 + w) * 512 + foff);
    SB_PIN_VMEM();
  } else if (!cons) {
    kan_feats28(Ach0 + tr * 232 + ej * 14, Hs[ej * 36 + tr]);  // chunk 0
  }
  bar();
#pragma unroll
  for (int c = 0; c < 16; ++c) {
    const bf16* const Ac = (c & 1) ? Ach1 : Ach0;
    bf16* const An = (c & 1) ? Ach0 : Ach1;
    if (w < 7) {
      if (c <= 11) KSTEP1(Ac, c, c + 4);
      else         KSTEP1(Ac, c, -1);
    } else if (!cons && c < 15) {
      kan_feats28(An + tr * 232 + ej * 14, Hs[((c + 1) * 16 + ej) * 36 + tr]);
    }
    bar();
  }
  if (w < 7) {
#pragma unroll
    for (int m = 0; m < 2; ++m)
#pragma unroll
      for (int r = 0; r < 4; ++r)
        Red[w * 512 + (m * 16 + quad * 4 + r) * 16 + lr] = acc3[m][r];
  }
  bar();
  if (t < 512) {
    float s = (ej < 10) ? b3[ej] : 0.f;
#pragma unroll
    for (int ks = 0; ks < 7; ++ks) s += Red[ks * 512 + tr * 16 + ej];
    V[tr * 16 + ej] = s;
  }
  bar();
  if (t < 32) {
    float vv[10];
#pragma unroll
    for (int o = 0; o < 10; ++o) vv[o] = V[t * 16 + o];
    float mx = vv[0];
#pragma unroll
    for (int o = 1; o < 10; ++o) mx = fmaxf(mx, vv[o]);
    float se = 0.f;
#pragma unroll
    for (int o = 0; o < 10; ++o) se += expf(vv[o] - mx);
    const float l = mx + logf(se);
#pragma unroll
    for (int o = 0; o < 10; ++o) out[(size_t)(r0 + t) * 10 + o] = vv[o] - l;
  }
}

extern "C" void kernel_launch(void* const* d_in, const int* in_sizes, int n_in,
                              void* d_out, int out_size, void* d_ws, size_t ws_size,
                              hipStream_t stream) {
  const float* x = (const float*)d_in[0];
  const float* coef1 = (const float*)d_in[1];
  const float* sb1 = (const float*)d_in[2];
  const float* sp1 = (const float*)d_in[3];
  const float* b1 = (const float*)d_in[4];
  const float* coef2 = (const float*)d_in[5];
  const float* sb2 = (const float*)d_in[6];
  const float* sp2 = (const float*)d_in[7];
  const float* b2 = (const float*)d_in[8];
  const float* coef3 = (const float*)d_in[9];
  const float* sb3 = (const float*)d_in[10];
  const float* sp3 = (const float*)d_in[11];
  const float* b3 = (const float*)d_in[12];
  float* out = (float*)d_out;

  char* ws = (char*)d_ws;
  bf16* W1f = (bf16*)ws;              // 22 frags x 16 ntg x 1KB = 360448 B
  bf16* W2f = (bf16*)(ws + 360448);   // 112 x 16 x 1KB = 1835008 B
  bf16* W3f = (bf16*)(ws + 2195456);  // 112 x 1KB = 114688 B

  prep_all<<<322, 256, 0, stream>>>(coef1, sb1, sp1, coef2, sb2, sp2,
                                    coef3, sb3, sp3, W1f, W2f, W3f);
  meganet<<<256, 1024, 0, stream>>>(x, W1f, W2f, W3f, b1, b2, b3, out);
}

// Round 7
// 139.140 us; speedup vs baseline: 1.2164x; 1.2164x over previous
//
#include <hip/hip_runtime.h>
#include <hip/hip_bf16.h>

typedef __bf16 bf16x8_t __attribute__((ext_vector_type(8)));
typedef float f32x4_t __attribute__((ext_vector_type(4)));
using bf16 = __hip_bfloat16;

__device__ __forceinline__ unsigned short f2bf_bits(float v) {
  __hip_bfloat16 h = __float2bfloat16(v);
  return *reinterpret_cast<unsigned short*>(&h);
}

// mish(x) = x*tanh(softplus(x)) = x*n/(n+2) with n = e^x*(e^x+2).
__device__ __forceinline__ float mish_f(float x) {
  float z = __expf(x);
  float n = z * (z + 2.0f);
  float m = x * n / (n + 2.0f);
  return (x > 10.0f) ? x : m;
}

// 13 cubic B-spline basis values (grid 10, k=3, [-2,2]) + mish -> 28B LDS
// region. R0 sparse-store version (branch-free selects doubled VALUBusy in
// R4 — keep sparse).
__device__ __forceinline__ void kan_feats28(bf16* dst, float x) {
  unsigned int* d32 = (unsigned int*)dst;
#pragma unroll
  for (int d = 0; d < 7; ++d) d32[d] = 0u;
  float t = (x + 3.2f) * 2.5f;
  if (t >= 0.0f && t < 16.0f) {
    float tf = floorf(t);
    int c = (int)tf;
    float u = t - tf;
    float um = 1.0f - u;
    float u2 = u * u, u3 = u2 * u;
    const float s6 = 1.0f / 6.0f;
    float w0 = um * um * um * s6;
    float w1 = (3.0f * u3 - 6.0f * u2 + 4.0f) * s6;
    float w2 = (-3.0f * u3 + 3.0f * u2 + 3.0f * u + 1.0f) * s6;
    float w3 = u3 * s6;
    int j0 = c - 3;
    if (j0 >= 0)               dst[j0]     = __float2bfloat16(w0);
    if (j0 >= -1 && j0 <= 11)  dst[j0 + 1] = __float2bfloat16(w1);
    if (j0 >= -2 && j0 <= 10)  dst[j0 + 2] = __float2bfloat16(w2);
    if (j0 <= 9)               dst[j0 + 3] = __float2bfloat16(w3);
  }
  dst[13] = __float2bfloat16(mish_f(x));
}

// Builds W1f, W2f, W3f — ALL MFMA-fragment-major. Frag s (global k-frag of 32)
// x ntg (group of 16 N-rows): 512 elements (1KB); element (n,quad,el) at
// (s*16+ntg)*512 + n*32 + quad*8 + el. Packed grid (322 blocks).
__global__ __launch_bounds__(256) void prep_all(
    const float* __restrict__ c1, const float* __restrict__ sb1, const float* __restrict__ sp1,
    const float* __restrict__ c2, const float* __restrict__ sb2, const float* __restrict__ sp2,
    const float* __restrict__ c3, const float* __restrict__ sb3, const float* __restrict__ sp3,
    bf16* __restrict__ W1f, bf16* __restrict__ W2f, bf16* __restrict__ W3f) {
  const int b = blockIdx.x, t = threadIdx.x;
  float vals[14];
  if (b < 49) {
    const int i = b, o = t;
    const int ntg = o >> 4, lrr = o & 15;
    const size_t io = (size_t)i * 256 + o;
    const float spv = sp1[io];
#pragma unroll
    for (int r = 0; r < 13; ++r) vals[r] = c1[io * 13 + r] * spv;
    vals[13] = sb1[io];
#pragma unroll
    for (int d = 0; d < 7; ++d) {
      const int k2 = i * 14 + 2 * d;
      const int s = k2 >> 5, r2 = k2 & 31;
      const size_t off = ((size_t)(s * 16 + ntg)) * 512 + lrr * 32 + (r2 >> 3) * 8 + (r2 & 7);
      *(unsigned int*)(W1f + off) = (unsigned int)f2bf_bits(vals[2 * d]) |
                                    ((unsigned int)f2bf_bits(vals[2 * d + 1]) << 16);
    }
  } else if (b == 49) {
    const int ntg = t >> 4, lrr = t & 15;
#pragma unroll
    for (int d = 0; d < 9; ++d) {
      const int k2 = 686 + 2 * d;
      const int r2 = k2 & 31;
      *(unsigned int*)(W1f + ((size_t)(21 * 16 + ntg)) * 512 + lrr * 32 + (r2 >> 3) * 8 + (r2 & 7)) = 0u;
    }
  } else if (b < 306) {
    const int i = b - 50;
    const int o = t;
    const int ntg = o >> 4, lrr = o & 15;
    const size_t io = (size_t)i * 256 + o;
    const float spv = sp2[io];
#pragma unroll
    for (int r = 0; r < 13; ++r) vals[r] = c2[io * 13 + r] * spv;
    vals[13] = sb2[io];
#pragma unroll
    for (int d = 0; d < 7; ++d) {
      const int k2 = i * 14 + 2 * d;
      const int s = k2 >> 5, r2 = k2 & 31;
      const size_t off = ((size_t)(s * 16 + ntg)) * 512 + lrr * 32 + (r2 >> 3) * 8 + (r2 & 7);
      *(unsigned int*)(W2f + off) = (unsigned int)f2bf_bits(vals[2 * d]) |
                                    ((unsigned int)f2bf_bits(vals[2 * d + 1]) << 16);
    }
  } else {
    const int idx = (b - 306) * 256 + t;  // 4096 items: i in [0,256), o in [0,16)
    const int i = idx >> 4, o = idx & 15;
    if (o < 10) {
      const size_t io = (size_t)i * 10 + o;
      const float spv = sp3[io];
#pragma unroll
      for (int r = 0; r < 13; ++r) vals[r] = c3[io * 13 + r] * spv;
      vals[13] = sb3[io];
#pragma unroll
      for (int d = 0; d < 7; ++d) {
        const int k2 = i * 14 + 2 * d;
        const int s = k2 >> 5, r2 = k2 & 31;
        const size_t off = (size_t)s * 512 + o * 32 + (r2 >> 3) * 8 + (r2 & 7);
        *(unsigned int*)(W3f + off) = (unsigned int)f2bf_bits(vals[2 * d]) |
                                      ((unsigned int)f2bf_bits(vals[2 * d + 1]) << 16);
      }
    } else {
#pragma unroll
      for (int d = 0; d < 7; ++d) {
        const int k2 = i * 14 + 2 * d;
        const int s = k2 >> 5, r2 = k2 & 31;
        *(unsigned int*)(W3f + (size_t)s * 512 + o * 32 + (r2 >> 3) * 8 + (r2 & 7)) = 0u;
      }
    }
  }
}

// Megakernel v12: R0 k-step machinery (plain loads, 4-deep compiler-placed
// FIFO, __syncthreads), but phases C and E run 32-col SUPER-chunks: 14
// k-steps per barrier (C) / 2 per wave (E), producers batch 2 feats evals.
// Barriers: C 16->8, E 16->8. A-buffers [32][472] bf16 (stride 472: 2-way
// bank alias on ds_read_b128, same as R0's 232).
__global__ __launch_bounds__(1024, 4) void meganet(
    const float* __restrict__ x, const bf16* __restrict__ W1f,
    const bf16* __restrict__ W2f, const bf16* __restrict__ W3f,
    const float* __restrict__ b1, const float* __restrict__ b2,
    const float* __restrict__ b3, float* __restrict__ out) {
  __shared__ __align__(16) char lds[104448];
  float* const Hs = (float*)lds;             // [256][36] f32 transposed (36864)
  bf16* const A0 = (bf16*)(lds + 36864);     // [32][472] bf16 (30208)
  bf16* const A1 = (bf16*)(lds + 67072);     // [32][472] bf16 (30208)
  float* const P = (float*)(lds + 97280);    // [32][56] f32 (7168)
  float* const xs = (float*)lds;             // phase A only (50176)
  float* const Red = (float*)(lds + 36864);  // [7][32][16] f32 (E tail)
  float* const V = (float*)(lds + 67072);    // 32x16 f32

  const int t = threadIdx.x;
  const int w = t >> 6, lane = t & 63, quad = lane >> 4, lr = lane & 15;
  const int tr = (t >> 4) & 31, ej = t & 15;  // producer eval coords (t>=512)
  const int r0 = blockIdx.x * 32;
  const int foff = lr * 32 + quad * 8;
  const bool cons = (w < 8);
  const int ntg0 = 2 * w;  // consumer col-group base (valid w<8)

  // ---- Phase A: pool 32 images -> P[32][56] (staged via LDS) ----
  for (int h = 0; h < 2; ++h) {
    const float4* src = (const float4*)x + (size_t)(r0 + h * 16) * 196;
    float4* xd = (float4*)xs;
#pragma unroll
    for (int l = 0; l < 4; ++l) {
      const int idx = t + l * 1024;
      if (idx < 3136) xd[idx] = src[idx];
    }
    __syncthreads();
    if (t < 784) {
      const int img = t / 49, p = t - img * 49;
      const int oh = p / 7, ow = p - oh * 7;
      const float* xi = xs + img * 784 + oh * 112 + ow * 4;
      f32x4_t s4 = (f32x4_t){0.f, 0.f, 0.f, 0.f};
#pragma unroll
      for (int rr = 0; rr < 4; ++rr) {
        const f32x4_t v = *(const f32x4_t*)(xi + rr * 28);  // 16B-aligned
        s4 += v;
      }
      P[(h * 16 + img) * 56 + p] = (s4[0] + s4[1] + s4[2] + s4[3]) * (1.0f / 16.0f);
    }
    __syncthreads();
  }

  f32x4_t acc[2][2];
#pragma unroll
  for (int m = 0; m < 2; ++m)
#pragma unroll
    for (int n = 0; n < 2; ++n) acc[m][n] = (f32x4_t){0.f, 0.f, 0.f, 0.f};

  // ---- Phase B: layer-1, K=704 (22 k-frags: chunks 7,7,7,1; stride 232,
  //      16-col chunks — verbatim R0, buffers aliased onto A0/A1) ----
  bf16* const Bch0 = A0;
  bf16* const Bch1 = A1;
  bf16x8_t q0[4], q1[4];
  if (cons) {
#pragma unroll
    for (int s = 0; s < 4; ++s) {
      q0[s] = *(const bf16x8_t*)(W1f + (size_t)(s * 16 + ntg0) * 512 + foff);
      q1[s] = *(const bf16x8_t*)(W1f + (size_t)(s * 16 + ntg0 + 1) * 512 + foff);
    }
  } else {
    kan_feats28(Bch0 + tr * 232 + ej * 14, P[tr * 56 + ej]);  // chunk 0
  }
  __syncthreads();
#pragma unroll
  for (int c = 0; c < 4; ++c) {
    const bf16* const Ac = (c & 1) ? Bch1 : Bch0;
    bf16* const An = (c & 1) ? Bch0 : Bch1;
    if (cons) {
      const int nks = (c < 3) ? 7 : 1;
#pragma unroll
      for (int ks = 0; ks < 7; ++ks) {
        if (ks >= nks) continue;
        const int kk = c * 7 + ks;
        const int sl = kk & 3;
        bf16x8_t bb0 = q0[sl], bb1 = q1[sl];
        if (kk + 4 < 22) {
          q0[sl] = *(const bf16x8_t*)(W1f + (size_t)((kk + 4) * 16 + ntg0) * 512 + foff);
          q1[sl] = *(const bf16x8_t*)(W1f + (size_t)((kk + 4) * 16 + ntg0 + 1) * 512 + foff);
        }
#pragma unroll
        for (int m = 0; m < 2; ++m) {
          bf16x8_t a = *(const bf16x8_t*)(Ac + (m * 16 + lr) * 232 + ks * 32 + quad * 8);
          acc[m][0] = __builtin_amdgcn_mfma_f32_16x16x32_bf16(a, bb0, acc[m][0], 0, 0, 0);
          acc[m][1] = __builtin_amdgcn_mfma_f32_16x16x32_bf16(a, bb1, acc[m][1], 0, 0, 0);
        }
      }
    } else {
      if (c < 2) {
        kan_feats28(An + tr * 232 + ej * 14, P[tr * 56 + (c + 1) * 16 + ej]);
      } else if (c == 2) {
        if (ej == 0) kan_feats28(An + tr * 232, P[tr * 56 + 48]);
        else if (ej == 1) {
          unsigned int* z = (unsigned int*)(An + tr * 232 + 14);
#pragma unroll
          for (int d = 0; d < 9; ++d) z[d] = 0u;  // pad k 686..703
        }
      }
    }
    __syncthreads();
  }
  // H1 = acc + b1 -> Hs (transposed); consumers cover all 256 cols
  if (cons) {
#pragma unroll
    for (int m = 0; m < 2; ++m)
#pragma unroll
      for (int n = 0; n < 2; ++n) {
        const int col = w * 32 + n * 16 + lr;
        const float bn = b1[col];
        f32x4_t v;
#pragma unroll
        for (int r = 0; r < 4; ++r) v[r] = acc[m][n][r] + bn;
        *(f32x4_t*)(Hs + col * 36 + m * 16 + quad * 4) = v;
      }
  }
  __syncthreads();

  // ---- Phase C: layer-2, K=3584. 8 super-chunks x 14 k-steps (32 H-cols,
  //      stride 472). Producers: 2 feats evals/thread per SC. ----
#pragma unroll
  for (int m = 0; m < 2; ++m)
#pragma unroll
    for (int n = 0; n < 2; ++n) acc[m][n] = (f32x4_t){0.f, 0.f, 0.f, 0.f};
  if (cons) {
#pragma unroll
    for (int s = 0; s < 4; ++s) {
      q0[s] = *(const bf16x8_t*)(W2f + (size_t)(s * 16 + ntg0) * 512 + foff);
      q1[s] = *(const bf16x8_t*)(W2f + (size_t)(s * 16 + ntg0 + 1) * 512 + foff);
    }
  } else {  // SC0: cols 0..31
    kan_feats28(A0 + tr * 472 + ej * 14, Hs[ej * 36 + tr]);
    kan_feats28(A0 + tr * 472 + (16 + ej) * 14, Hs[(16 + ej) * 36 + tr]);
  }
  __syncthreads();
#pragma unroll
  for (int S = 0; S < 8; ++S) {
    const bf16* const Ac = (S & 1) ? A1 : A0;
    bf16* const An = (S & 1) ? A0 : A1;
    if (cons) {
#pragma unroll
      for (int ks = 0; ks < 14; ++ks) {
        const int kk = S * 14 + ks;
        const int sl = kk & 3;
        bf16x8_t bb0 = q0[sl], bb1 = q1[sl];
        if (kk + 4 < 112) {
          q0[sl] = *(const bf16x8_t*)(W2f + (size_t)((kk + 4) * 16 + ntg0) * 512 + foff);
          q1[sl] = *(const bf16x8_t*)(W2f + (size_t)((kk + 4) * 16 + ntg0 + 1) * 512 + foff);
        }
#pragma unroll
        for (int m = 0; m < 2; ++m) {
          bf16x8_t a = *(const bf16x8_t*)(Ac + (m * 16 + lr) * 472 + ks * 32 + quad * 8);
          acc[m][0] = __builtin_amdgcn_mfma_f32_16x16x32_bf16(a, bb0, acc[m][0], 0, 0, 0);
          acc[m][1] = __builtin_amdgcn_mfma_f32_16x16x32_bf16(a, bb1, acc[m][1], 0, 0, 0);
        }
      }
    } else if (S < 7) {
      const int col = 32 * (S + 1);
      kan_feats28(An + tr * 472 + ej * 14, Hs[(col + ej) * 36 + tr]);
      kan_feats28(An + tr * 472 + (16 + ej) * 14, Hs[(col + 16 + ej) * 36 + tr]);
    }
    __syncthreads();
  }
  // H2 = acc + b2 -> Hs (overwrite; H1 dead after SC7 feats)
  if (cons) {
#pragma unroll
    for (int m = 0; m < 2; ++m)
#pragma unroll
      for (int n = 0; n < 2; ++n) {
        const int col = w * 32 + n * 16 + lr;
        const float bn = b2[col];
        f32x4_t v;
#pragma unroll
        for (int r = 0; r < 4; ++r) v[r] = acc[m][n][r] + bn;
        *(f32x4_t*)(Hs + col * 36 + m * 16 + quad * 4) = v;
      }
  }
  __syncthreads();

  // ---- Phase E: layer-3 (N=16, 10 real). 8 super-chunks; consumer waves
  //      0..6 do 2 k-steps each per SC (k-slots w and w+7); producers =
  //      waves 8..15 (2 feats evals/thread per SC). ----
  f32x4_t acc3[2];
  acc3[0] = (f32x4_t){0.f, 0.f, 0.f, 0.f};
  acc3[1] = acc3[0];
  bf16x8_t q3[4];
  if (w < 7) {
#pragma unroll
    for (int s = 0; s < 4; ++s)
      q3[s] = *(const bf16x8_t*)(W3f + (size_t)(s * 7 + w) * 512 + foff);
  } else if (!cons) {  // SC0: cols 0..31
    kan_feats28(A0 + tr * 472 + ej * 14, Hs[ej * 36 + tr]);
    kan_feats28(A0 + tr * 472 + (16 + ej) * 14, Hs[(16 + ej) * 36 + tr]);
  }
  __syncthreads();
#pragma unroll
  for (int S = 0; S < 8; ++S) {
    const bf16* const Ac = (S & 1) ? A1 : A0;
    bf16* const An = (S & 1) ? A0 : A1;
    if (w < 7) {
      {  // k-step 1: frag-chunk c0 = 2S, local ks = w
        const int c0 = 2 * S;
        bf16x8_t bb = q3[c0 & 3];
        if (c0 + 4 < 16)
          q3[c0 & 3] = *(const bf16x8_t*)(W3f + (size_t)((c0 + 4) * 7 + w) * 512 + foff);
        bf16x8_t a0 = *(const bf16x8_t*)(Ac + lr * 472 + w * 32 + quad * 8);
        bf16x8_t a1 = *(const bf16x8_t*)(Ac + (16 + lr) * 472 + w * 32 + quad * 8);
        acc3[0] = __builtin_amdgcn_mfma_f32_16x16x32_bf16(a0, bb, acc3[0], 0, 0, 0);
        acc3[1] = __builtin_amdgcn_mfma_f32_16x16x32_bf16(a1, bb, acc3[1], 0, 0, 0);
      }
      {  // k-step 2: frag-chunk c1 = 2S+1, local ks = w+7
        const int c1 = 2 * S + 1;
        bf16x8_t bb = q3[c1 & 3];
        if (c1 + 4 < 16)
          q3[c1 & 3] = *(const bf16x8_t*)(W3f + (size_t)((c1 + 4) * 7 + w) * 512 + foff);
        bf16x8_t a0 = *(const bf16x8_t*)(Ac + lr * 472 + (w + 7) * 32 + quad * 8);
        bf16x8_t a1 = *(const bf16x8_t*)(Ac + (16 + lr) * 472 + (w + 7) * 32 + quad * 8);
        acc3[0] = __builtin_amdgcn_mfma_f32_16x16x32_bf16(a0, bb, acc3[0], 0, 0, 0);
        acc3[1] = __builtin_amdgcn_mfma_f32_16x16x32_bf16(a1, bb, acc3[1], 0, 0, 0);
      }
    } else if (!cons && S < 7) {
      const int col = 32 * (S + 1);
      kan_feats28(An + tr * 472 + ej * 14, Hs[(col + ej) * 36 + tr]);
      kan_feats28(An + tr * 472 + (16 + ej) * 14, Hs[(col + 16 + ej) * 36 + tr]);
    }
    __syncthreads();
  }
  if (w < 7) {
#pragma unroll
    for (int m = 0; m < 2; ++m)
#pragma unroll
      for (int r = 0; r < 4; ++r)
        Red[w * 512 + (m * 16 + quad * 4 + r) * 16 + lr] = acc3[m][r];
  }
  __syncthreads();
  if (t < 512) {
    float s = (ej < 10) ? b3[ej] : 0.f;
#pragma unroll
    for (int ks = 0; ks < 7; ++ks) s += Red[ks * 512 + tr * 16 + ej];
    V[tr * 16 + ej] = s;
  }
  __syncthreads();
  if (t < 32) {
    float vv[10];
#pragma unroll
    for (int o = 0; o < 10; ++o) vv[o] = V[t * 16 + o];
    float mx = vv[0];
#pragma unroll
    for (int o = 1; o < 10; ++o) mx = fmaxf(mx, vv[o]);
    float se = 0.f;
#pragma unroll
    for (int o = 0; o < 10; ++o) se += expf(vv[o] - mx);
    const float l = mx + logf(se);
#pragma unroll
    for (int o = 0; o < 10; ++o) out[(size_t)(r0 + t) * 10 + o] = vv[o] - l;
  }
}

extern "C" void kernel_launch(void* const* d_in, const int* in_sizes, int n_in,
                              void* d_out, int out_size, void* d_ws, size_t ws_size,
                              hipStream_t stream) {
  const float* x = (const float*)d_in[0];
  const float* coef1 = (const float*)d_in[1];
  const float* sb1 = (const float*)d_in[2];
  const float* sp1 = (const float*)d_in[3];
  const float* b1 = (const float*)d_in[4];
  const float* coef2 = (const float*)d_in[5];
  const float* sb2 = (const float*)d_in[6];
  const float* sp2 = (const float*)d_in[7];
  const float* b2 = (const float*)d_in[8];
  const float* coef3 = (const float*)d_in[9];
  const float* sb3 = (const float*)d_in[10];
  const float* sp3 = (const float*)d_in[11];
  const float* b3 = (const float*)d_in[12];
  float* out = (float*)d_out;

  char* ws = (char*)d_ws;
  bf16* W1f = (bf16*)ws;              // 22 frags x 16 ntg x 1KB = 360448 B
  bf16* W2f = (bf16*)(ws + 360448);   // 112 x 16 x 1KB = 1835008 B
  bf16* W3f = (bf16*)(ws + 2195456);  // 112 x 1KB = 114688 B

  prep_all<<<322, 256, 0, stream>>>(coef1, sb1, sp1, coef2, sb2, sp2,
                                    coef3, sb3, sp3, W1f, W2f, W3f);
  meganet<<<256, 1024, 0, stream>>>(x, W1f, W2f, W3f, b1, b2, b3, out);
}